// Round 5
// baseline (625.614 us; speedup 1.0000x reference)
//
#include <hip/hip_runtime.h>

// x [4,2048,4096] f32, dna [6] f32, bias [4096] f32, hd [4096,4096] i32,
// out [4,2048,4096] f32. Internally W and X are cast to bf16 for the MFMA GEMM.
#define M_DIM 4096
#define K_DIM 4096
#define NR_DIM 8192
#define TOTAL_ELEMS (M_DIM * K_DIM)
#define X_ELEMS (NR_DIM * K_DIM)

typedef unsigned short u16;
typedef unsigned int u32;
typedef __bf16 bf16x8 __attribute__((ext_vector_type(8)));
typedef float f32x4 __attribute__((ext_vector_type(4)));
typedef u16 u16x8 __attribute__((ext_vector_type(8)));

__device__ __forceinline__ u16 f2b(float f) {
    u32 v;
    __builtin_memcpy(&v, &f, sizeof(v));
    v += 0x7FFFu + ((v >> 16) & 1u);  // round-to-nearest-even
    return (u16)(v >> 16);
}

// Inline |sin|,|cos| via Cody-Waite + minimax polys. Signs are irrelevant
// downstream (fabs), so quadrant handling is a parity swap only.
__device__ __forceinline__ void abs_sincos(float ang, float* s, float* c) {
    float q = rintf(ang * 0.636619772f);
    float r1 = fmaf(q, -1.57079637e+00f, ang);
    float r = fmaf(q, 4.37113883e-08f, r1);
    float r2 = r * r;
    float ts = fmaf(r2, -1.9840874e-04f, 8.3333310e-03f);
    ts = fmaf(r2, ts, -1.6666667e-01f);
    float sp = fmaf(r * r2, ts, r);
    float tc = fmaf(r2, -1.3888378e-03f, 4.1666638e-02f);
    tc = fmaf(r2, tc, -5.0e-01f);
    float cp = fmaf(r2, tc, 1.0f);
    bool sw = (((int)q) & 1) != 0;
    *s = sw ? cp : sp;
    *c = sw ? sp : cp;
}

// FAST path (actual dna: a==b==1, n1==n2==n3==0.5):
// r = 1 / (sqrt|cos| + sqrt|sin|)^2, base in [1,1.68].
__device__ __forceinline__ float compute_r_fast(int d, float c_ang) {
    float s, c;
    abs_sincos((float)d * c_ang, &s, &c);
    float base = __builtin_amdgcn_sqrtf(fabsf(c)) + __builtin_amdgcn_sqrtf(fabsf(s));
    return __builtin_amdgcn_rcpf(base * base);
}

// GENERIC path for arbitrary dna — wave-uniform-selected, cold.
__device__ __noinline__ float compute_r_gen(int d, float c_ang, float inv_a,
                                            float inv_b, float n2, float n3, float e) {
    float s, c;
    abs_sincos((float)d * c_ang, &s, &c);
    float ca = fabsf(c) * fabsf(inv_a);
    float sb = fabsf(s) * fabsf(inv_b);
    float t1 = (n2 == 0.5f) ? sqrtf(ca) : ((n2 == 1.0f) ? ca : powf(ca, n2));
    float t2 = (n3 == 0.5f) ? sqrtf(sb) : ((n3 == 1.0f) ? sb : powf(sb, n3));
    float base = t1 + t2;
    if (e == -2.0f) { float ib = __builtin_amdgcn_rcpf(base); return ib * ib; }
    if (e == -1.0f) return __builtin_amdgcn_rcpf(base);
    return powf(base, e);
}

__device__ __forceinline__ bool dna_is_fast(const float* p) {
    return (p[1] == 1.0f) & (p[2] == 1.0f) & (p[3] == 0.5f) &
           (p[4] == 0.5f) & (p[5] == 0.5f);
}

// Fused prologue: x f32->bf16 conversion (memory-bound) + r-statistics
// reduction (VALU-bound, d = linear index since Hilbert d is a bijection on
// [0,2^24) and mean/std are order-invariant). Interleaved in one loop so the
// reduce compute hides under the convert's memory latency.
// Grid: 2048 x 256 = 524288 threads. 32 reduce elems + 16 float4 convert
// chunks per thread.
__global__ void __launch_bounds__(256) prologue_kernel(const float* __restrict__ x,
                                                       const float* __restrict__ dna,
                                                       u16* __restrict__ xb,
                                                       double* __restrict__ sums) {
    float p[6];
#pragma unroll
    for (int i = 0; i < 6; i++) p[i] = dna[i];
    float c_ang = (float)((double)p[0] * 6.283185307179586 / 67108864.0);

    const int tid = blockIdx.x * blockDim.x + threadIdx.x;
    const int nthreads = 2048 * 256;

    double s = 0.0, s2 = 0.0;
    if (dna_is_fast(p)) {
#pragma unroll 2
        for (int it = 0; it < 32; it++) {
            // convert: 16 chunks of float4
            if (it < 16) {
                int c = tid + it * nthreads;         // chunk index < 8.39M
                float4 a = *(const float4*)(x + (size_t)c * 4);
                ushort4 o;
                o.x = f2b(a.x); o.y = f2b(a.y); o.z = f2b(a.z); o.w = f2b(a.w);
                *(ushort4*)(xb + (size_t)c * 4) = o;
            }
            // reduce: 32 elements
            int d = tid + it * nthreads;
            float r = compute_r_fast(d, c_ang);
            s += (double)r;
            s2 += (double)r * (double)r;
        }
    } else {
        float inv_a = 1.0f / p[1], inv_b = 1.0f / p[2], e = -1.0f / p[3];
        for (int it = 0; it < 32; it++) {
            if (it < 16) {
                int c = tid + it * nthreads;
                float4 a = *(const float4*)(x + (size_t)c * 4);
                ushort4 o;
                o.x = f2b(a.x); o.y = f2b(a.y); o.z = f2b(a.z); o.w = f2b(a.w);
                *(ushort4*)(xb + (size_t)c * 4) = o;
            }
            int d = tid + it * nthreads;
            float r = compute_r_gen(d, c_ang, inv_a, inv_b, p[4], p[5], e);
            s += (double)r;
            s2 += (double)r * (double)r;
        }
    }

#pragma unroll
    for (int off = 32; off > 0; off >>= 1) {
        s += __shfl_down(s, off);
        s2 += __shfl_down(s2, off);
    }
    __shared__ double ls[4], ls2[4];
    int lane = threadIdx.x & 63, w = threadIdx.x >> 6;
    if (lane == 0) { ls[w] = s; ls2[w] = s2; }
    __syncthreads();
    if (threadIdx.x == 0) {
        atomicAdd(&sums[0], ls[0] + ls[1] + ls[2] + ls[3]);
        atomicAdd(&sums[1], ls2[0] + ls2[1] + ls2[2] + ls2[3]);
    }
}

// W[m,k] = (r - mean)/(std_ddof1 + 1e-9) * (1/sqrt(K)), stored bf16.
__global__ void __launch_bounds__(256) build_w_kernel(const int* __restrict__ hd,
                                                      const float* __restrict__ dna,
                                                      const double* __restrict__ sums,
                                                      u16* __restrict__ W) {
    float p[6];
#pragma unroll
    for (int i = 0; i < 6; i++) p[i] = dna[i];
    float c_ang = (float)((double)p[0] * 6.283185307179586 / 67108864.0);

    const double cnt = (double)TOTAL_ELEMS;
    double sum = sums[0], sumsq = sums[1];
    float meanf = (float)(sum / cnt);
    float stdf = (float)sqrt((sumsq - sum * sum / cnt) / (cnt - 1.0));
    float sc = 0.015625f / (stdf + 1e-9f);  // fold 1/sqrt(4096)

    int idx = blockIdx.x * blockDim.x + threadIdx.x;
    int stride = gridDim.x * blockDim.x;
    if (dna_is_fast(p)) {
        for (int i = idx * 4; i < TOTAL_ELEMS; i += stride * 4) {
            int4 d4 = *(const int4*)(hd + i);
            ushort4 o;
            o.x = f2b((compute_r_fast(d4.x, c_ang) - meanf) * sc);
            o.y = f2b((compute_r_fast(d4.y, c_ang) - meanf) * sc);
            o.z = f2b((compute_r_fast(d4.z, c_ang) - meanf) * sc);
            o.w = f2b((compute_r_fast(d4.w, c_ang) - meanf) * sc);
            *(ushort4*)(W + i) = o;
        }
    } else {
        float inv_a = 1.0f / p[1], inv_b = 1.0f / p[2], e = -1.0f / p[3];
        for (int i = idx * 4; i < TOTAL_ELEMS; i += stride * 4) {
            int4 d4 = *(const int4*)(hd + i);
            ushort4 o;
            o.x = f2b((compute_r_gen(d4.x, c_ang, inv_a, inv_b, p[4], p[5], e) - meanf) * sc);
            o.y = f2b((compute_r_gen(d4.y, c_ang, inv_a, inv_b, p[4], p[5], e) - meanf) * sc);
            o.z = f2b((compute_r_gen(d4.z, c_ang, inv_a, inv_b, p[4], p[5], e) - meanf) * sc);
            o.w = f2b((compute_r_gen(d4.w, c_ang, inv_a, inv_b, p[4], p[5], e) - meanf) * sc);
            *(ushort4*)(W + i) = o;
        }
    }
}

// ---------------- GEMM: C[NR,M] = X[NR,K] * W[M,K]^T -----------------------
// m97 structure + XOR swizzle on 16B LDS chunks (round 3: conflicts -> 0).
// UNCHANGED — control dispatch.
#define TM 128
#define TN 128
#define TK 64

__device__ __forceinline__ void gld_lds16(const u16* g, u16* l) {
    __builtin_amdgcn_global_load_lds(
        (const __attribute__((address_space(1))) void*)g,
        (__attribute__((address_space(3))) void*)l,
        16, 0, 0);
}

__global__ void __launch_bounds__(256) gemm_kernel(const u16* __restrict__ A,
                                                   const u16* __restrict__ B,
                                                   const float* __restrict__ bias,
                                                   float* __restrict__ C) {
    __shared__ __align__(16) u16 As[TM * TK];
    __shared__ __align__(16) u16 Bs[TN * TK];

    const int t = threadIdx.x;
    const int lane = t & 63;
    const int wave = t >> 6;
    const int wr = wave >> 1;
    const int wc = wave & 1;
    const int lrow = lane & 15;
    const int lq = lane >> 4;
    const int sw8 = lrow & 7;

    const long i0 = (long)blockIdx.y * TM;
    const long j0 = (long)blockIdx.x * TN;

    const int srow = t >> 3;
    const int scol = (((t & 7) ^ (srow & 7)) * 8);
    const int ldst = srow * TK + (t & 7) * 8;

    const f32x4 vzero = {0.f, 0.f, 0.f, 0.f};
    f32x4 acc[4][4];
#pragma unroll
    for (int a = 0; a < 4; a++)
#pragma unroll
        for (int b = 0; b < 4; b++) acc[a][b] = vzero;

    const u16* Ab = A + i0 * K_DIM;
    const u16* Bb = B + j0 * K_DIM;

    for (int k0 = 0; k0 < K_DIM; k0 += TK) {
#pragma unroll
        for (int q = 0; q < 4; q++) {
            int row = srow + q * 32;
            gld_lds16(Ab + (long)row * K_DIM + k0 + scol, &As[ldst + q * 32 * TK]);
        }
#pragma unroll
        for (int q = 0; q < 4; q++) {
            int row = srow + q * 32;
            gld_lds16(Bb + (long)row * K_DIM + k0 + scol, &Bs[ldst + q * 32 * TK]);
        }
        __syncthreads();

#pragma unroll
        for (int kk = 0; kk < TK; kk += 32) {
            const int kc = (kk >> 3) + lq;
            bf16x8 af[4], bfr[4];
#pragma unroll
            for (int mi = 0; mi < 4; mi++) {
                int row = wr * 64 + mi * 16 + lrow;
                af[mi] = *(const bf16x8*)(&As[row * TK + ((kc ^ sw8) << 3)]);
            }
#pragma unroll
            for (int ni = 0; ni < 4; ni++) {
                int row = wc * 64 + ni * 16 + lrow;
                bfr[ni] = *(const bf16x8*)(&Bs[row * TK + ((kc ^ sw8) << 3)]);
            }
#pragma unroll
            for (int mi = 0; mi < 4; mi++)
#pragma unroll
                for (int ni = 0; ni < 4; ni++)
                    acc[mi][ni] = __builtin_amdgcn_mfma_f32_16x16x32_bf16(
                        af[mi], bfr[ni], acc[mi][ni], 0, 0, 0);
        }
        __syncthreads();
    }

#pragma unroll
    for (int ni = 0; ni < 4; ni++) {
        long j = j0 + wc * 64 + ni * 16 + lrow;
        float bv = bias[j];
#pragma unroll
        for (int mi = 0; mi < 4; mi++) {
            long ib = i0 + wr * 64 + mi * 16 + lq * 4;
#pragma unroll
            for (int r = 0; r < 4; r++) {
                C[(ib + r) * M_DIM + j] = acc[mi][ni][r] + bv;
            }
        }
    }
}

extern "C" void kernel_launch(void* const* d_in, const int* in_sizes, int n_in,
                              void* d_out, int out_size, void* d_ws, size_t ws_size,
                              hipStream_t stream) {
    const float* x = (const float*)d_in[0];
    const float* dna = (const float*)d_in[1];
    const float* bias = (const float*)d_in[2];
    const int* hd = (const int*)d_in[3];
    float* out = (float*)d_out;

    double* sums = (double*)d_ws;                                   // 16 B
    u16* W = (u16*)((char*)d_ws + 256);                             // 32 MB bf16
    u16* Xb = (u16*)((char*)d_ws + 256 + (size_t)TOTAL_ELEMS * 2);  // 64 MB bf16

    hipMemsetAsync(d_ws, 0, 256, stream);
    prologue_kernel<<<dim3(2048), dim3(256), 0, stream>>>(x, dna, Xb, sums);
    build_w_kernel<<<dim3(2048), dim3(256), 0, stream>>>(hd, dna, sums, W);
    gemm_kernel<<<dim3(M_DIM / TN, NR_DIM / TM), dim3(256), 0, stream>>>(Xb, W, bias, out);
}